// Round 1
// baseline (121.958 us; speedup 1.0000x reference)
//
#include <hip/hip_runtime.h>

#define MEM_SIZE 16777216
#define N4 (MEM_SIZE / 4)

// ---- faithful soft-gate math (fp32, mirrors reference formulas) ----

__device__ __forceinline__ float silu_f(float x) {
    return x / (1.0f + __expf(-x));
}

// silu_threshold(x, s=20) = (silu(20x+10) - silu(20x-10)) / 20
__device__ __forceinline__ float silu_th(float x) {
    float d = 20.0f * x;
    return (silu_f(d + 10.0f) - silu_f(d - 10.0f)) * 0.05f;
}

__device__ __forceinline__ float eq_g(float a, float b) {
    float diff = a - b;
    return silu_th(diff + 0.5f) * silu_th(0.5f - diff);
}
__device__ __forceinline__ float ge_g(float a, float b) { return silu_th(a - b + 0.5f); }
__device__ __forceinline__ float gt_g(float a, float b) { return silu_th(a - b - 0.5f); }

__device__ __forceinline__ float swiglu_mul_f(float a, float b) {
    return a * silu_f(b) - a * silu_f(-b);
}

__device__ __forceinline__ float pulse_f(float x, float c) {
    float d = x - c;
    return swiglu_mul_f(silu_th(d + 0.5f), silu_th(0.5f - d));
}

// Windowed soft-attention read: eq_gate support is |addr-pos| < ~2.5;
// beyond +/-5 contributions are < 1e-26 (below fp32 rounding of the result).
__device__ float read_mem_soft(const float* mem, float addr) {
    float ca = rintf(addr);
    if (!(ca > -16.0f && ca < (float)MEM_SIZE + 16.0f)) return 0.0f;
    int c = (int)ca;
    float wsum = 0.0f, vsum = 0.0f;
    for (int d = -5; d <= 5; ++d) {
        int i = c + d;
        if (i < 0 || i >= MEM_SIZE) continue;
        float w = eq_g(addr, (float)i);
        wsum += w;
        vsum += w * mem[i];
    }
    return vsum / (wsum + 1e-8f);
}

// Block 0: full scalar VM step.  Blocks 1..N-1: memory copy to out+4.
__global__ __launch_bounds__(256) void k_main(
    const float* __restrict__ pc_p, const float* __restrict__ sp_p,
    const float* __restrict__ bp_p, const float* __restrict__ ax_p,
    const float* __restrict__ mem, float* __restrict__ out,
    float* __restrict__ ws)
{
    if (blockIdx.x != 0) {
        const float4* src = (const float4*)mem;
        float4* dst = (float4*)(out + 4);   // out base 256B-aligned -> +16B still 16B-aligned
        int stride = (int)(gridDim.x - 1) * 256;
        for (int i = ((int)blockIdx.x - 1) * 256 + (int)threadIdx.x; i < N4; i += stride)
            dst[i] = src[i];
        return;
    }

    __shared__ float s_reads[5];
    __shared__ float sred[256];
    __shared__ float sres[3];
    int t = threadIdx.x;

    float pc = pc_p[0], sp = sp_p[0], bp = bp_p[0], ax = ax_p[0];

    if (t < 5) {
        float addr = (t == 0) ? pc
                   : (t == 1) ? sp
                   : (t == 2) ? ax
                   : (t == 3) ? bp
                              : (sp + 8.0f);
        s_reads[t] = read_mem_soft(mem, addr);
    }
    __syncthreads();

    float instruction   = s_reads[0];
    float stack_top     = s_reads[1];
    float li_result     = s_reads[2];
    float bp_from_stack = s_reads[3];
    float pc_from_stack = s_reads[4];

    float ax_safe = ax + eq_g(ax, 0.0f);

    // ---- swiglu_div: 256 quotient terms, one per thread ----
    {
        float q  = (float)t;
        float t1 = stack_top - q * ax_safe + 0.5f;
        float t2 = stack_top - (q + 1.0f) * ax_safe + 0.5f;
        sred[t] = (silu_th(t1) - silu_th(t2)) * q;
    }
    __syncthreads();
    for (int off = 128; off >= 1; off >>= 1) {
        if (t < off) sred[t] += sred[t + off];
        __syncthreads();
    }
    if (t == 0) sres[0] = sred[0];
    __syncthreads();

    // ---- shifts: 32 terms ----
    float shlterm = 0.0f, shrterm = 0.0f;
    if (t < 32) {
        float p  = ldexpf(1.0f, t);          // 2^i exact
        float pl = pulse_f(ax, (float)t);
        shlterm = swiglu_mul_f(stack_top, p) * pl;
        shrterm = floorf(stack_top / p) * pl;
    }
    sred[t] = shlterm;
    __syncthreads();
    for (int off = 128; off >= 1; off >>= 1) {
        if (t < off) sred[t] += sred[t + off];
        __syncthreads();
    }
    if (t == 0) sres[1] = sred[0];
    __syncthreads();
    sred[t] = shrterm;
    __syncthreads();
    for (int off = 128; off >= 1; off >>= 1) {
        if (t < off) sred[t] += sred[t + off];
        __syncthreads();
    }
    if (t == 0) sres[2] = sred[0];
    __syncthreads();

    if (t != 0) return;

    // ---- scalar tail on thread 0 ----
    float pc_next = pc + 8.0f;
    float imm     = floorf(instruction * (1.0f / 256.0f));
    float opcode  = instruction - imm * 256.0f;   // jnp.remainder(x,256) (divisor sign)

    float add_result = stack_top + ax;
    float sub_result = stack_top - ax;
    float mul_result = swiglu_mul_f(stack_top, ax);
    float div_result = sres[0];
    float mod_result = stack_top - swiglu_mul_f(div_result, ax_safe);
    float shl_result = sres[1];
    float shr_result = sres[2];
    float or_result  = stack_top + ax - swiglu_mul_f(stack_top, ax);
    float xor_result = stack_top + ax - 2.0f * swiglu_mul_f(stack_top, ax);
    float and_result = swiglu_mul_f(stack_top, ax);
    float eq_result  = eq_g(stack_top, ax);
    float ne_result  = 1.0f - eq_g(stack_top, ax);
    float lt_result  = gt_g(ax, stack_top);
    float gt_result  = gt_g(stack_top, ax);
    float le_result  = ge_g(ax, stack_top);
    float ge_result  = ge_g(stack_top, ax);
    float lc_result  = li_result;
    float lea_result = bp + imm;

    // opcodes: LEA=0 IMM=1 JMP=2 JSR=3 BZ=4 BNZ=5 ENT=6 ADJ=7 LEV=8 LI=9 LC=10
    //          SI=11 SC=12 PSH=13 OR=14 XOR=15 AND=16 EQ=17 NE=18 LT=19 GT=20
    //          LE=21 GE=22 SHL=23 SHR=24 ADD=25 SUB=26 MUL=27 DIV=28 MOD=29
    float g_lea = eq_g(opcode, 0.0f),  g_imm = eq_g(opcode, 1.0f);
    float g_jmp = eq_g(opcode, 2.0f),  g_jsr = eq_g(opcode, 3.0f);
    float g_bz  = eq_g(opcode, 4.0f),  g_bnz = eq_g(opcode, 5.0f);
    float g_ent = eq_g(opcode, 6.0f),  g_adj = eq_g(opcode, 7.0f);
    float g_lev = eq_g(opcode, 8.0f),  g_li  = eq_g(opcode, 9.0f);
    float g_lc  = eq_g(opcode, 10.0f), g_si  = eq_g(opcode, 11.0f);
    float g_sc  = eq_g(opcode, 12.0f), g_psh = eq_g(opcode, 13.0f);
    float g_or  = eq_g(opcode, 14.0f), g_xor = eq_g(opcode, 15.0f);
    float g_and = eq_g(opcode, 16.0f), g_eq  = eq_g(opcode, 17.0f);
    float g_ne  = eq_g(opcode, 18.0f), g_lt  = eq_g(opcode, 19.0f);
    float g_gt  = eq_g(opcode, 20.0f), g_le  = eq_g(opcode, 21.0f);
    float g_ge  = eq_g(opcode, 22.0f), g_shl = eq_g(opcode, 23.0f);
    float g_shr = eq_g(opcode, 24.0f), g_add = eq_g(opcode, 25.0f);
    float g_sub = eq_g(opcode, 26.0f), g_mul = eq_g(opcode, 27.0f);
    float g_div = eq_g(opcode, 28.0f), g_mod = eq_g(opcode, 29.0f);

    float gate_sum = g_lea + g_imm + g_li + g_lc + g_add + g_sub + g_mul + g_div
                   + g_mod + g_shl + g_shr + g_or + g_xor + g_and + g_eq + g_ne
                   + g_lt + g_gt + g_le + g_ge;
    float new_ax = ax * (1.0f - gate_sum)
        + lea_result * g_lea + imm * g_imm + li_result * g_li + lc_result * g_lc
        + add_result * g_add + sub_result * g_sub + mul_result * g_mul
        + div_result * g_div + mod_result * g_mod + shl_result * g_shl
        + shr_result * g_shr + or_result * g_or + xor_result * g_xor
        + and_result * g_and + eq_result * g_eq + ne_result * g_ne
        + lt_result * g_lt + gt_result * g_gt + le_result * g_le + ge_result * g_ge;

    float pops = g_add + g_sub + g_mul + g_div + g_mod + g_shl + g_shr + g_or + g_xor
               + g_and + g_eq + g_ne + g_lt + g_gt + g_le + g_ge;
    float new_sp = sp * (1.0f - g_psh - g_adj - g_ent - g_lev - pops)
        + (sp - 8.0f) * g_psh + (sp + imm) * g_adj + (sp - imm) * g_ent
        + bp * g_lev + (sp + 8.0f) * pops;

    float new_bp = bp * (1.0f - g_ent - g_lev) + sp * g_ent + bp_from_stack * g_lev;

    float eq_ax0   = eq_g(ax, 0.0f);
    float bz_take  = swiglu_mul_f(g_bz, eq_ax0);
    float bnz_take = swiglu_mul_f(g_bnz, 1.0f - eq_ax0);
    float new_pc = pc_next * (1.0f - g_jmp - g_jsr - bz_take - bnz_take - g_lev)
        + imm * g_jmp + imm * g_jsr + imm * bz_take + imm * bnz_take
        + pc_from_stack * g_lev;

    out[0] = rintf(new_pc);
    out[1] = rintf(new_sp);
    out[2] = rintf(new_bp);
    out[3] = rintf(new_ax);

    // write descriptors (addr, value) in reference order: psh, jsr, ent, si, sc
    ws[0] = (sp - 8.0f) * g_psh;  ws[1] = ax * g_psh;
    ws[2] = (sp - 8.0f) * g_jsr;  ws[3] = pc_next * g_jsr;
    ws[4] = (sp - 8.0f) * g_ent;  ws[5] = bp * g_ent;
    ws[6] = stack_top * g_si;     ws[7] = ax * g_si;
    ws[8] = stack_top * g_sc;     ws[9] = ax * g_sc;
}

// Apply the 5 soft writes to the copied memory. Each candidate slot is
// processed by exactly one thread (smallest write index whose window contains
// it), which applies ALL 5 writes in reference order.
__global__ void k_patch(float* __restrict__ out, const float* __restrict__ ws) {
    const int R = 6, W = 2 * R + 1;        // 13-slot window per write
    int t = threadIdx.x;
    if (t >= 5 * W) return;
    int j = t / W;
    int d = t % W - R;

    float addr_j = ws[2 * j];
    float cj = rintf(addr_j);
    if (!(cj > -64.0f && cj < (float)MEM_SIZE + 64.0f)) return;
    int slot = (int)cj + d;
    if (slot < 0 || slot >= MEM_SIZE) return;

    for (int j2 = 0; j2 < j; ++j2) {
        float c2 = rintf(ws[2 * j2]);
        if (c2 > -64.0f && c2 < (float)MEM_SIZE + 64.0f) {
            int cc = (int)c2;
            if (slot >= cc - R && slot <= cc + R) return;  // earlier thread owns it
        }
    }

    float fs = (float)slot;
    float m = out[4 + slot];
    #pragma unroll
    for (int jj = 0; jj < 5; ++jj) {
        float a = ws[2 * jj], v = ws[2 * jj + 1];
        float g = eq_g(a, fs);
        m = m * (1.0f - g) + v * g;
    }
    out[4 + slot] = m;
}

extern "C" void kernel_launch(void* const* d_in, const int* in_sizes, int n_in,
                              void* d_out, int out_size, void* d_ws, size_t ws_size,
                              hipStream_t stream) {
    const float* pc  = (const float*)d_in[0];
    const float* sp  = (const float*)d_in[1];
    const float* bp  = (const float*)d_in[2];
    const float* ax  = (const float*)d_in[3];
    const float* mem = (const float*)d_in[4];
    float* out = (float*)d_out;
    float* ws  = (float*)d_ws;

    const int copy_blocks = 4096;
    hipLaunchKernelGGL(k_main, dim3(copy_blocks + 1), dim3(256), 0, stream,
                       pc, sp, bp, ax, mem, out, ws);
    hipLaunchKernelGGL(k_patch, dim3(1), dim3(128), 0, stream, out, ws);
}